// Round 1
// baseline (351.560 us; speedup 1.0000x reference)
//
#include <hip/hip_runtime.h>

// HiPPO-LegT projection: c_{t+1} = A c_t + B f_t, emit all states.
// Strategy: chunked linear recurrence as GEMM.
//   out[64k+tau] = A^{tau+1} c_{64k} + sum_{j<=tau} A^{tau-j} B f_{64k+j}
// Per chunk k: GEMM M=2048(seq) x N=4096(tau,n) x K=128([c0|f]).
// Weight table Tg[col=(tau*64+n)][kk] (fp16, transposed for B-frag b128 reads):
//   kk in [0,64):   Tg[col][m]    = A^{tau+1}[n][m]          (carry part)
//   kk in [64,128): Tg[col][64+j] = (j<=tau) ? K_{tau-j}[n] : 0, K_i = A^i B
// Precompute: power_kernel (64 blocks, block d computes A^d by binary exp in
// f32 LDS, writes V-slab + K_d), pack_kernel (gathers K into W part).
// Main: 8 sequential chunk_gemm launches; chunk k reads carry from the
// out[64k-1] slab written by launch k-1 (same-stream ordering).

typedef _Float16 half8  __attribute__((ext_vector_type(8)));
typedef _Float16 half4t __attribute__((ext_vector_type(4)));
typedef float    f32x4  __attribute__((ext_vector_type(4)));

#define SEQN 2048
#define LT   512

// ---------------------------------------------------------------------------
// 64x64 f32 matmul in LDS: C = X*Y given XT (X transposed) and Y.
// 512 threads, each computes a 4x2 output block. Optionally writes result
// transposed (outT) and/or normal (outN), in place is safe (reads finish
// before the internal barrier).
__device__ __forceinline__ void mul64(const float* XT, const float* Y,
                                      float* outT, float* outN, int t) {
  const int r = (t >> 5) * 4;
  const int c = (t & 31) * 2;
  float a00 = 0.f, a01 = 0.f, a10 = 0.f, a11 = 0.f;
  float a20 = 0.f, a21 = 0.f, a30 = 0.f, a31 = 0.f;
#pragma unroll 4
  for (int l = 0; l < 64; ++l) {
    const float4 x = *(const float4*)(XT + l * 64 + r);
    const float2 y = *(const float2*)(Y + l * 64 + c);
    a00 += x.x * y.x; a01 += x.x * y.y;
    a10 += x.y * y.x; a11 += x.y * y.y;
    a20 += x.z * y.x; a21 += x.z * y.y;
    a30 += x.w * y.x; a31 += x.w * y.y;
  }
  __syncthreads();
  if (outT) {
    outT[(c + 0) * 64 + r + 0] = a00; outT[(c + 1) * 64 + r + 0] = a01;
    outT[(c + 0) * 64 + r + 1] = a10; outT[(c + 1) * 64 + r + 1] = a11;
    outT[(c + 0) * 64 + r + 2] = a20; outT[(c + 1) * 64 + r + 2] = a21;
    outT[(c + 0) * 64 + r + 3] = a30; outT[(c + 1) * 64 + r + 3] = a31;
  }
  if (outN) {
    outN[(r + 0) * 64 + c + 0] = a00; outN[(r + 0) * 64 + c + 1] = a01;
    outN[(r + 1) * 64 + c + 0] = a10; outN[(r + 1) * 64 + c + 1] = a11;
    outN[(r + 2) * 64 + c + 0] = a20; outN[(r + 2) * 64 + c + 1] = a21;
    outN[(r + 3) * 64 + c + 0] = a30; outN[(r + 3) * 64 + c + 1] = a31;
  }
  __syncthreads();
}

// Block d (= blockIdx.x+1, 1..64): compute A^d, write V-slab for tau=d-1 and
// K_d = A^d B. All-f32 to keep the power chain accurate; fp16 only at output.
__global__ __launch_bounds__(512) void power_kernel(
    const float* __restrict__ A, const float* __restrict__ B,
    _Float16* __restrict__ Tg, float* __restrict__ Kg) {
  __shared__ float S[4096];    // current square-chain power (normal)
  __shared__ float STr[4096];  // same, transposed
  __shared__ float RT[4096];   // accumulated result, transposed
  const int t = threadIdx.x;
  const int d = blockIdx.x + 1;

  for (int i = t; i < 4096; i += 512) {
    const float v = A[i];
    S[i] = v;
    STr[(i & 63) * 64 + (i >> 6)] = v;
  }
  __syncthreads();

  bool rvalid = false;
  int e = d;
  while (e) {
    if (e & 1) {
      if (!rvalid) {
        for (int i = t; i < 4096; i += 512) RT[i] = STr[i];  // R = S
        rvalid = true;
        __syncthreads();
      } else {
        mul64(RT, S, RT, nullptr, t);  // R = R*S (store transposed)
      }
    }
    e >>= 1;
    if (e) mul64(STr, S, STr, S, t);   // S = S*S (both forms)
  }
  // RT[m*64+n] = (A^d)[n][m]
  // V-slab: Tg[((d-1)*64+n)][m] = A^d[n][m]
  for (int i = t; i < 4096; i += 512) {
    const int n = i >> 6, m = i & 63;
    Tg[(size_t)((d - 1) * 64 + n) * 128 + m] = (_Float16)RT[m * 64 + n];
  }
  // K_d = A^d B (f32), plus K_0 = B from block 1.
  if (d < 64 && t < 64) {
    float s = 0.f;
    for (int m = 0; m < 64; ++m) s += RT[m * 64 + t] * B[m];
    Kg[d * 64 + t] = s;
  }
  if (d == 1 && t < 64) Kg[t] = B[t];
}

// Block tau: fill W part of table: Tg[(tau*64+n)][64+j] = (j<=tau)?K_{tau-j}[n]:0
__global__ __launch_bounds__(256) void pack_kernel(
    const float* __restrict__ Kg, _Float16* __restrict__ Tg) {
  const int tau = blockIdx.x;
  const int t = threadIdx.x;
  const int n = t >> 2;
  const int j0 = (t & 3) * 16;
#pragma unroll
  for (int jj = 0; jj < 16; ++jj) {
    const int j = j0 + jj;
    const _Float16 v =
        (j <= tau) ? (_Float16)Kg[(tau - j) * 64 + n] : (_Float16)0.f;
    Tg[(size_t)(tau * 64 + n) * 128 + 64 + j] = v;
  }
}

// Chunk GEMM: out-tile 128(seq) x 128(col=(tau,n)), K=128.
// 4 waves in 2x2; each wave: 64x64 via 4x4 grid of 16x16x32 f16 MFMA.
__global__ __launch_bounds__(256) void chunk_gemm(
    const float* __restrict__ f, const _Float16* __restrict__ Tg,
    const float* __restrict__ carry, float* __restrict__ out, int chunk) {
  __shared__ _Float16 Xs[128 * 136];  // [seq-local][k] (pad: +8 -> 2-way max)
  __shared__ _Float16 Ws[128 * 72];   // [col-local][kw] one 64-wide K half

  const int tid = threadIdx.x;
  const int bn = blockIdx.x;  // 0..31 N-tiles
  const int bm = blockIdx.y;  // 0..15 M-tiles
  const int lane = tid & 63, wid = tid >> 6;
  const int wm = wid >> 1, wn = wid & 1;
  const int l15 = lane & 15, quad = lane >> 4;

  // ---- stage X = [c0 | f] (f32 -> f16) ----
  {
    const int r = tid >> 1, h = tid & 1;
    const int seq = bm * 128 + r;
    if (h == 0) {
      if (carry) {
        const float4* s = (const float4*)(carry + (size_t)seq * 64);
#pragma unroll
        for (int i = 0; i < 16; ++i) {
          const float4 v = s[i];
          half4t hv = {(_Float16)v.x, (_Float16)v.y, (_Float16)v.z,
                       (_Float16)v.w};
          *(half4t*)&Xs[r * 136 + i * 4] = hv;
        }
      }
    } else {
      const float4* s = (const float4*)(f + (size_t)seq * LT + chunk * 64);
#pragma unroll
      for (int i = 0; i < 16; ++i) {
        const float4 v = s[i];
        half4t hv = {(_Float16)v.x, (_Float16)v.y, (_Float16)v.z,
                     (_Float16)v.w};
        *(half4t*)&Xs[r * 136 + 64 + i * 4] = hv;
      }
    }
  }

  f32x4 acc[4][4];
  const f32x4 z = {0.f, 0.f, 0.f, 0.f};
#pragma unroll
  for (int i = 0; i < 4; ++i)
#pragma unroll
    for (int j = 0; j < 4; ++j) acc[i][j] = z;

  const int kh0 = carry ? 0 : 1;  // chunk 0: carry is zero, skip that K half
  for (int kh = kh0; kh < 2; ++kh) {
    if (kh != kh0) __syncthreads();  // protect Ws before overwrite
    // ---- stage W half (transposed table rows, contiguous 64B per thread) ----
    {
      const int col = tid >> 1, h = tid & 1;
      const uint4* s = (const uint4*)(Tg + (size_t)(bn * 128 + col) * 128 +
                                      kh * 64 + h * 32);
#pragma unroll
      for (int i = 0; i < 4; ++i)
        *(uint4*)&Ws[col * 72 + h * 32 + i * 8] = s[i];
    }
    __syncthreads();

#pragma unroll
    for (int kk = 0; kk < 2; ++kk) {
      half8 av[4], bv[4];
#pragma unroll
      for (int fm = 0; fm < 4; ++fm)
        av[fm] = *(const half8*)&Xs[(wm * 64 + fm * 16 + l15) * 136 + kh * 64 +
                                    kk * 32 + quad * 8];
#pragma unroll
      for (int fn = 0; fn < 4; ++fn)
        bv[fn] = *(const half8*)&Ws[(wn * 64 + fn * 16 + l15) * 72 + kk * 32 +
                                    quad * 8];
#pragma unroll
      for (int fm = 0; fm < 4; ++fm)
#pragma unroll
        for (int fn = 0; fn < 4; ++fn)
          acc[fm][fn] = __builtin_amdgcn_mfma_f32_16x16x32_f16(
              av[fm], bv[fn], acc[fm][fn], 0, 0, 0);
    }
  }

  // ---- epilogue: D row = quad*4+reg (seq), col = lane&15 (n) ----
  const int taug = chunk * 64 + bn * 2 + wn;  // global t of this wave's slab
#pragma unroll
  for (int fm = 0; fm < 4; ++fm) {
#pragma unroll
    for (int r = 0; r < 4; ++r) {
      const size_t row =
          (size_t)taug * SEQN + (bm * 128 + wm * 64 + fm * 16 + quad * 4 + r);
      float* o = out + row * 64 + l15;
#pragma unroll
      for (int fn = 0; fn < 4; ++fn) o[fn * 16] = acc[fm][fn][r];
    }
  }
}

extern "C" void kernel_launch(void* const* d_in, const int* in_sizes, int n_in,
                              void* d_out, int out_size, void* d_ws,
                              size_t ws_size, hipStream_t stream) {
  const float* f = (const float*)d_in[0];  // (16,128,512) -> (2048, 512)
  const float* A = (const float*)d_in[1];  // (64,64)
  const float* B = (const float*)d_in[2];  // (64,)
  float* out = (float*)d_out;              // (512, 2048, 64)

  _Float16* Tg = (_Float16*)d_ws;                       // 4096 x 128 f16 = 1 MB
  float* Kg = (float*)((char*)d_ws + 4096 * 128 * 2);   // 64 x 64 f32

  power_kernel<<<64, 512, 0, stream>>>(A, B, Tg, Kg);
  pack_kernel<<<64, 256, 0, stream>>>(Kg, Tg);
  for (int k = 0; k < 8; ++k) {
    const float* carry =
        (k == 0) ? nullptr : out + (size_t)(64 * k - 1) * SEQN * 64;
    chunk_gemm<<<dim3(32, 16), 256, 0, stream>>>(f, Tg, carry, out, k);
  }
}